// Round 3
// baseline (438.075 us; speedup 1.0000x reference)
//
#include <hip/hip_runtime.h>
#include <hip/hip_bf16.h>
#include <math.h>

#define Mdim 2048
#define FD   128
#define NEG  (-1e30f)
#define BSTR 136   // bf16 elems per LDS B row: 128 + 8 pad (272 B, 16B-aligned)

typedef __attribute__((ext_vector_type(8))) short short8;
typedef __attribute__((ext_vector_type(4))) float f32x4;

// ---------- Kernel 1: fp64 row norms + normalized bf16 copy ----------
__global__ void prep_kernel(const float* __restrict__ x,
                            double* __restrict__ nrm_d,
                            unsigned short* __restrict__ xnb) {
    int row = blockIdx.x * 4 + (threadIdx.x >> 6);   // one wave per row
    int lane = threadIdx.x & 63;
    const float* p = x + (size_t)row * FD;
    float v0 = p[lane], v1 = p[lane + 64];
    double d = (double)v0 * (double)v0 + (double)v1 * (double)v1;
    #pragma unroll
    for (int off = 32; off; off >>= 1) d += __shfl_down(d, off);
    d = __shfl(d, 0);
    double nrm = fmax(sqrt(d), 1e-12);
    if (lane == 0) nrm_d[row] = nrm;
    double inv = 1.0 / nrm;
    __hip_bfloat16 ha = __float2bfloat16((float)((double)v0 * inv));
    __hip_bfloat16 hb = __float2bfloat16((float)((double)v1 * inv));
    unsigned short* q = xnb + (size_t)row * FD;
    q[lane]      = *reinterpret_cast<unsigned short*>(&ha);
    q[lane + 64] = *reinterpret_cast<unsigned short*>(&hb);
}

// branchless sorted-desc top-3 insert (pure cndmask)
__device__ __forceinline__ void ins3(float v, int n, float tv[3], int ti[3]) {
    bool g2 = v > tv[2], g1 = v > tv[1], g0 = v > tv[0];
    tv[2] = g1 ? tv[1] : (g2 ? v : tv[2]);
    ti[2] = g1 ? ti[1] : (g2 ? n : ti[2]);
    tv[1] = g0 ? tv[0] : (g1 ? v : tv[1]);
    ti[1] = g0 ? ti[0] : (g1 ? n : ti[1]);
    tv[0] = g0 ? v : tv[0];
    ti[0] = g0 ? n : ti[0];
}

// sorted-desc top-8 insert with early-out (merge phase, 32 active lanes)
__device__ __forceinline__ void ins8(float v, int n, float bv[8], int bi[8]) {
    if (v <= bv[7]) return;
    #pragma unroll
    for (int s = 0; s < 8; ++s) {
        if (v > bv[s]) {
            float ov = bv[s]; int oi = bi[s];
            bv[s] = v; bi[s] = n;
            v = ov; n = oi;
        }
    }
}

// ---------- Kernel 2: MFMA GEMM + top-k + fp64 refine + dense row write ----------
__launch_bounds__(256, 2)
__global__ void topk_kernel(const float* __restrict__ x,
                            const unsigned short* __restrict__ xnb,
                            const double* __restrict__ nrm_d,
                            float* __restrict__ out,
                            int2* __restrict__ tops_i,
                            float2* __restrict__ tops_v) {
    // LDS map:
    // [0, 34816)            Bld: 128 cols x BSTR bf16   (reused: mval[96][32], midx[96][32])
    // [34816, 36864)        fval: 32 rows x 8 doubles
    // [36864, 37888)        fidx: 256 ints
    // [37888, 38144)        selI: 32 int2
    // [38144, 38400)        selV: 32 float2
    __shared__ __align__(16) char smem[38400];
    unsigned short* Bld = (unsigned short*)smem;

    int b  = blockIdx.x >> 6;          // batch (64 row-tiles per batch)
    int rt = blockIdx.x & 63;
    int row0 = rt * 32;
    const unsigned short* xb = xnb + (size_t)b * Mdim * FD;

    int tid  = threadIdx.x;
    int lane = tid & 63;
    int w    = tid >> 6;
    int wy   = w >> 1, wx = w & 1;     // 2x2 wave grid: 16 rows x 64 cols per wave
    int c    = lane & 15, q = lane >> 4;

    // A fragments in registers: rows row0 + wy*16 + c
    short8 afr[4];
    #pragma unroll
    for (int s = 0; s < 4; ++s)
        afr[s] = *(const short8*)(xb + (size_t)(row0 + wy*16 + c) * FD + s*32 + q*8);

    // per-lane top-3 per row-reg i (row m_i = row0 + wy*16 + q*4 + i)
    float tv[4][3]; int ti[4][3];
    #pragma unroll
    for (int i = 0; i < 4; ++i)
        #pragma unroll
        for (int j = 0; j < 3; ++j) { tv[i][j] = NEG; ti[i][j] = -1; }

    #pragma unroll 1
    for (int ch = 0; ch < Mdim / 128; ++ch) {
        int col0 = ch * 128;
        __syncthreads();
        {   // stage 128 cols x 128 k bf16 -> LDS (padded stride)
            int col = tid >> 1, hf = tid & 1;
            const short8* src = (const short8*)(xb + (size_t)(col0 + col) * FD + hf*64);
            unsigned short* dst = Bld + col * BSTR + hf*64;
            #pragma unroll
            for (int i = 0; i < 8; ++i)
                *(short8*)(dst + i*8) = src[i];
        }
        __syncthreads();

        f32x4 acc[4];
        #pragma unroll
        for (int ct = 0; ct < 4; ++ct) acc[ct] = (f32x4){0.f, 0.f, 0.f, 0.f};

        #pragma unroll
        for (int s = 0; s < 4; ++s)
            #pragma unroll
            for (int ct = 0; ct < 4; ++ct) {
                short8 bfr = *(const short8*)(Bld + (size_t)(wx*64 + ct*16 + c) * BSTR + s*32 + q*8);
                acc[ct] = __builtin_amdgcn_mfma_f32_16x16x32_bf16(afr[s], bfr, acc[ct], 0, 0, 0);
            }

        // scan (diagonal NOT excluded; dropped by index at final select)
        int nbase = col0 + wx*64 + c;
        #pragma unroll
        for (int i = 0; i < 4; ++i) {
            float v0 = acc[0][i], v1 = acc[1][i], v2 = acc[2][i], v3 = acc[3][i];
            float mx = fmaxf(fmaxf(v0, v1), fmaxf(v2, v3));
            if (mx > tv[i][2]) {
                ins3(v0, nbase,      tv[i], ti[i]);
                ins3(v1, nbase + 16, tv[i], ti[i]);
                ins3(v2, nbase + 32, tv[i], ti[i]);
                ins3(v3, nbase + 48, tv[i], ti[i]);
            }
        }
    }

    // ---- merge: per-lane top-3 -> per-row pool of 96, conflict-free [slot][row] ----
    __syncthreads();
    float* mval = (float*)smem;             // [96][32]
    int*   midx = (int*)(smem + 12288);     // [96][32]
    {
        int slot = wx*16 + c;               // 0..31
        #pragma unroll
        for (int i = 0; i < 4; ++i) {
            int r = wy*16 + q*4 + i;        // 0..31
            #pragma unroll
            for (int j = 0; j < 3; ++j) {
                mval[(slot*3 + j)*32 + r] = tv[i][j];
                midx[(slot*3 + j)*32 + r] = ti[i][j];
            }
        }
    }
    __syncthreads();

    double* fval = (double*)(smem + 34816);
    int*    fidx = (int*)(smem + 36864);
    if (tid < 32) {
        float bv[8]; int bi[8];
        #pragma unroll
        for (int s = 0; s < 8; ++s) { bv[s] = NEG; bi[s] = -1; }
        for (int s2 = 0; s2 < 96; ++s2)
            ins8(mval[s2*32 + tid], midx[s2*32 + tid], bv, bi);
        #pragma unroll
        for (int s = 0; s < 8; ++s) fidx[tid*8 + s] = bi[s];
    }
    __syncthreads();

    // ---- fp64 refinement: 256 candidates, 1 per thread ----
    const float*  xf = x + (size_t)b * Mdim * FD;
    const double* nb = nrm_d + (size_t)b * Mdim;
    {
        int r = tid >> 3;
        int n = fidx[tid];
        int m = row0 + r;
        const f32x4* pm = (const f32x4*)(xf + (size_t)m * FD);
        const f32x4* pn = (const f32x4*)(xf + (size_t)n * FD);
        double a0 = 0.0, a1 = 0.0;
        #pragma unroll 4
        for (int k4 = 0; k4 < FD/4; k4 += 2) {
            f32x4 u0 = pm[k4],   vv0 = pn[k4];
            f32x4 u1 = pm[k4+1], vv1 = pn[k4+1];
            a0 = fma((double)u0[0], (double)vv0[0], a0);
            a0 = fma((double)u0[1], (double)vv0[1], a0);
            a0 = fma((double)u0[2], (double)vv0[2], a0);
            a0 = fma((double)u0[3], (double)vv0[3], a0);
            a1 = fma((double)u1[0], (double)vv1[0], a1);
            a1 = fma((double)u1[1], (double)vv1[1], a1);
            a1 = fma((double)u1[2], (double)vv1[2], a1);
            a1 = fma((double)u1[3], (double)vv1[3], a1);
        }
        fval[tid] = (a0 + a1) / (nb[m] * nb[n]);
    }
    __syncthreads();

    // ---- exact top-2 (skip diagonal by index) + publish selection ----
    int2*   selI = (int2*)(smem + 37888);
    float2* selV = (float2*)(smem + 38144);
    if (tid < 32) {
        int m = row0 + tid;
        const double* fv = fval + tid*8;
        const int*    fi = fidx + tid*8;
        int c1 = -1, c2 = -1;
        for (int cc = 0; cc < 8; ++cc) {
            if (fi[cc] == m) continue;   // drop self-similarity (diag)
            if (c1 < 0 || fv[cc] > fv[c1] || (fv[cc] == fv[c1] && fi[cc] < fi[c1])) { c2 = c1; c1 = cc; }
            else if (c2 < 0 || fv[cc] > fv[c2] || (fv[cc] == fv[c2] && fi[cc] < fi[c2])) { c2 = cc; }
        }
        double v1 = fv[c1]; int i1 = fi[c1];
        double v2 = fv[c2]; int i2 = fi[c2];
        // reference top_k competes against the zeroed diagonal (value 0):
        // val1 always scatters; val2 only if it beats the diagonal zero.
        int  i2w = (v2 > 0.0) ? i2 : -1;
        int2   si = make_int2(i1, i2w);
        float2 sv = make_float2((float)(0.5 * v1), (float)(0.5 * v2));
        selI[tid] = si; selV[tid] = sv;
        tops_i[(size_t)b * Mdim + m] = si;
        tops_v[(size_t)b * Mdim + m] = sv;
    }
    __syncthreads();

    // ---- dense row write: zeros + own halved top-2 (replaces global memset) ----
    {
        size_t obase = (size_t)b * Mdim * Mdim;
        int r = tid >> 3, seg = tid & 7;           // 8 threads per row, 256 floats each
        float4* orow = (float4*)(out + obase + (size_t)(row0 + r) * Mdim + seg * 256);
        float4 z = make_float4(0.f, 0.f, 0.f, 0.f);
        #pragma unroll 8
        for (int k = 0; k < 64; ++k) orow[k] = z;
    }
    __syncthreads();
    if (tid < 32) {
        size_t obase = (size_t)b * Mdim * Mdim + (size_t)(row0 + tid) * Mdim;
        int2 si = selI[tid]; float2 sv = selV[tid];
        out[obase + si.x] = sv.x;
        if (si.y >= 0) out[obase + si.y] = sv.y;
    }
}

// ---------- Kernel 3: transpose contributions (unique-writer, non-atomic) ----------
__global__ void transpose_kernel(const int2* __restrict__ tops_i,
                                 const float2* __restrict__ tops_v,
                                 float* out) {
    int id = blockIdx.x * 256 + threadIdx.x;   // 0 .. B*M-1
    int b = id >> 11, m = id & (Mdim - 1);
    int2 si = tops_i[id]; float2 sv = tops_v[id];
    float* ob = out + (size_t)b * Mdim * Mdim;
    float* p1 = ob + (size_t)si.x * Mdim + m;  // column m: only row m writes here
    *p1 += sv.x;
    if (si.y >= 0) {
        float* p2 = ob + (size_t)si.y * Mdim + m;
        *p2 += sv.y;
    }
}

extern "C" void kernel_launch(void* const* d_in, const int* in_sizes, int n_in,
                              void* d_out, int out_size, void* d_ws, size_t ws_size,
                              hipStream_t stream) {
    const float* x = (const float*)d_in[0];
    float* out = (float*)d_out;
    int Bn = in_sizes[0] / (Mdim * FD);   // 16

    char* ws = (char*)d_ws;
    double*         nrm_d  = (double*)ws;                            // 256 KB
    unsigned short* xnb    = (unsigned short*)(ws + 262144);         // 8 MB
    int2*           tops_i = (int2*)(ws + 262144 + 8388608);         // 256 KB
    float2*         tops_v = (float2*)(ws + 262144 + 8388608 + 262144); // 256 KB

    prep_kernel<<<Bn * Mdim / 4, 256, 0, stream>>>(x, nrm_d, xnb);
    topk_kernel<<<Bn * 64, 256, 0, stream>>>(x, xnb, nrm_d, out, tops_i, tops_v);
    transpose_kernel<<<Bn * Mdim / 256, 256, 0, stream>>>(tops_i, tops_v, out);
}

// Round 4
// 365.618 us; speedup vs baseline: 1.1982x; 1.1982x over previous
//
#include <hip/hip_runtime.h>
#include <hip/hip_bf16.h>
#include <math.h>

#define Mdim 2048
#define FD   128
#define NEG  (-1e30f)

// LDS map (bytes). Bld [0,32768) is reused by mval/midx after the GEMM loop.
#define OFF_MVAL 0          // float[64][97] = 24832
#define OFF_MIDX 24832      // int[64][97]   = 24832 -> 49664
#define OFF_FVAL 49664      // double[64][9] = 4608  -> 54272
#define OFF_FIDX 54272      // int[64][9]    = 2304  -> 56576
#define SMEM_SZ  56576

typedef __attribute__((ext_vector_type(8))) short short8;
typedef __attribute__((ext_vector_type(4))) float f32x4;

// ---------- Kernel 1: fp64 row norms + normalized bf16 copy ----------
__global__ void prep_kernel(const float* __restrict__ x,
                            double* __restrict__ nrm_d,
                            unsigned short* __restrict__ xnb) {
    int row = blockIdx.x * 4 + (threadIdx.x >> 6);   // one wave per row
    int lane = threadIdx.x & 63;
    const float* p = x + (size_t)row * FD;
    float v0 = p[lane], v1 = p[lane + 64];
    double d = (double)v0 * (double)v0 + (double)v1 * (double)v1;
    #pragma unroll
    for (int off = 32; off; off >>= 1) d += __shfl_down(d, off);
    d = __shfl(d, 0);
    double nrm = fmax(sqrt(d), 1e-12);
    if (lane == 0) nrm_d[row] = nrm;
    double inv = 1.0 / nrm;
    __hip_bfloat16 ha = __float2bfloat16((float)((double)v0 * inv));
    __hip_bfloat16 hb = __float2bfloat16((float)((double)v1 * inv));
    unsigned short* q = xnb + (size_t)row * FD;
    q[lane]      = *reinterpret_cast<unsigned short*>(&ha);
    q[lane + 64] = *reinterpret_cast<unsigned short*>(&hb);
}

// branchless sorted-desc top-3 insert (pure cndmask)
__device__ __forceinline__ void ins3(float v, int n, float tv[3], int ti[3]) {
    bool g2 = v > tv[2], g1 = v > tv[1], g0 = v > tv[0];
    tv[2] = g1 ? tv[1] : (g2 ? v : tv[2]);
    ti[2] = g1 ? ti[1] : (g2 ? n : ti[2]);
    tv[1] = g0 ? tv[0] : (g1 ? v : tv[1]);
    ti[1] = g0 ? ti[0] : (g1 ? n : ti[1]);
    tv[0] = g0 ? v : tv[0];
    ti[0] = g0 ? n : ti[0];
}

// sorted-desc top-8 insert with early-out (merge phase)
__device__ __forceinline__ void ins8(float v, int n, float bv[8], int bi[8]) {
    if (v <= bv[7]) return;
    #pragma unroll
    for (int s = 0; s < 8; ++s) {
        if (v > bv[s]) {
            float ov = bv[s]; int oi = bi[s];
            bv[s] = v; bi[s] = n;
            v = ov; n = oi;
        }
    }
}

// ---------- Kernel 2: MFMA GEMM + top-k + fp64 refine + dense row write ----------
__launch_bounds__(256, 2)
__global__ void topk_kernel(const float* __restrict__ x,
                            const unsigned short* __restrict__ xnb,
                            const double* __restrict__ nrm_d,
                            float* __restrict__ out,
                            int2* __restrict__ tops_i,
                            float2* __restrict__ tops_v) {
    __shared__ __align__(16) char smem[SMEM_SZ];
    unsigned short* Bld = (unsigned short*)smem;  // [128 cols][128 k] bf16, 16B-chunk XOR swizzle

    int b  = blockIdx.x >> 5;          // 32 row-tiles (of 64 rows) per batch
    int rt = blockIdx.x & 31;
    int row0 = rt * 64;
    const unsigned short* xb = xnb + (size_t)b * Mdim * FD;

    int tid  = threadIdx.x;
    int lane = tid & 63;
    int w    = tid >> 6;
    int wy   = w >> 1, wx = w & 1;     // 2x2 wave grid; wave tile = 32 rows x 64 cols
    int c    = lane & 15, q = lane >> 4;

    // A fragments in registers for entire kernel: 2 row-subtiles x 4 k-steps
    short8 afr[2][4];
    #pragma unroll
    for (int rs = 0; rs < 2; ++rs)
        #pragma unroll
        for (int s = 0; s < 4; ++s)
            afr[rs][s] = *(const short8*)(xb + (size_t)(row0 + wy*32 + rs*16 + c) * FD + s*32 + q*8);

    // per-lane top-3 per owned row (8 rows/lane); diag competes, dropped at select
    float tv[8][3]; int ti[8][3];
    #pragma unroll
    for (int i = 0; i < 8; ++i)
        #pragma unroll
        for (int j = 0; j < 3; ++j) { tv[i][j] = NEG; ti[i][j] = -1; }

    // streaming zero-writer base: 8 rows x 32 float4 per chunk per thread block-slice
    float* zbase = out + (size_t)b * Mdim * Mdim
                 + (size_t)(row0 + (tid >> 5)) * Mdim + (tid & 31) * 4;

    #pragma unroll 1
    for (int ch = 0; ch < Mdim / 128; ++ch) {
        int col0 = ch * 128;
        __syncthreads();
        {   // stage 128 cols x 128 k bf16 -> LDS, XOR-swizzled (conflict-free)
            int col = tid >> 1, hf = tid & 1;
            const short8* src = (const short8*)(xb + (size_t)(col0 + col) * FD + hf*64);
            unsigned short* dstc = Bld + col * 128;
            int sw = col & 15;
            #pragma unroll
            for (int i = 0; i < 8; ++i) {
                int j = (hf*8 + i) ^ sw;
                *(short8*)(dstc + j*8) = src[i];
            }
        }
        __syncthreads();

        // zero-write this chunk's output slice (overlaps with MFMA/scan latency)
        {
            float4 z = make_float4(0.f, 0.f, 0.f, 0.f);
            #pragma unroll
            for (int t = 0; t < 8; ++t)
                *(float4*)(zbase + (size_t)t * 8 * Mdim) = z;
            zbase += 128;
        }

        f32x4 acc[2][4];
        #pragma unroll
        for (int rs = 0; rs < 2; ++rs)
            #pragma unroll
            for (int ct = 0; ct < 4; ++ct)
                acc[rs][ct] = (f32x4){0.f, 0.f, 0.f, 0.f};

        #pragma unroll
        for (int s = 0; s < 4; ++s)
            #pragma unroll
            for (int ct = 0; ct < 4; ++ct) {
                short8 bfr = *(const short8*)(Bld + (size_t)(wx*64 + ct*16 + c) * 128
                                              + (((s << 2) + q) ^ c) * 8);
                acc[0][ct] = __builtin_amdgcn_mfma_f32_16x16x32_bf16(afr[0][s], bfr, acc[0][ct], 0, 0, 0);
                acc[1][ct] = __builtin_amdgcn_mfma_f32_16x16x32_bf16(afr[1][s], bfr, acc[1][ct], 0, 0, 0);
            }

        // scan (diag included; dropped by index at final select)
        int nbase = col0 + wx*64 + c;
        #pragma unroll
        for (int rs = 0; rs < 2; ++rs)
            #pragma unroll
            for (int i = 0; i < 4; ++i) {
                int rr = rs*4 + i;
                float v0 = acc[rs][0][i], v1 = acc[rs][1][i], v2 = acc[rs][2][i], v3 = acc[rs][3][i];
                float mx = fmaxf(fmaxf(v0, v1), fmaxf(v2, v3));
                if (mx > tv[rr][2]) {
                    ins3(v0, nbase,      tv[rr], ti[rr]);
                    ins3(v1, nbase + 16, tv[rr], ti[rr]);
                    ins3(v2, nbase + 32, tv[rr], ti[rr]);
                    ins3(v3, nbase + 48, tv[rr], ti[rr]);
                }
            }
    }

    // ---- merge: per-lane top-3 -> per-row pool of 96 (stride-97: conflict-light) ----
    __syncthreads();
    float* mval = (float*)(smem + OFF_MVAL);
    int*   midx = (int*)(smem + OFF_MIDX);
    {
        int slot = wx*16 + c;               // 0..31
        #pragma unroll
        for (int rs = 0; rs < 2; ++rs)
            #pragma unroll
            for (int i = 0; i < 4; ++i) {
                int rloc = wy*32 + rs*16 + q*4 + i;   // 0..63
                #pragma unroll
                for (int j = 0; j < 3; ++j) {
                    mval[rloc*97 + slot*3 + j] = tv[rs*4 + i][j];
                    midx[rloc*97 + slot*3 + j] = ti[rs*4 + i][j];
                }
            }
    }
    __syncthreads();

    double* fval = (double*)(smem + OFF_FVAL);   // [64][9]
    int*    fidx = (int*)(smem + OFF_FIDX);      // [64][9]
    if (tid < 64) {
        float bv[8]; int bi[8];
        #pragma unroll
        for (int s = 0; s < 8; ++s) { bv[s] = NEG; bi[s] = -1; }
        for (int s2 = 0; s2 < 96; ++s2)
            ins8(mval[tid*97 + s2], midx[tid*97 + s2], bv, bi);
        #pragma unroll
        for (int s = 0; s < 8; ++s) fidx[tid*9 + s] = bi[s];
    }
    __syncthreads();

    // ---- fp64 refinement: 512 candidates, 2 per thread ----
    const float*  xf = x + (size_t)b * Mdim * FD;
    const double* nb = nrm_d + (size_t)b * Mdim;
    #pragma unroll
    for (int it = 0; it < 2; ++it) {
        int id = tid + it * 256;
        int r = id >> 3, sl = id & 7;
        int n = fidx[r*9 + sl];
        int m = row0 + r;
        const f32x4* pm = (const f32x4*)(xf + (size_t)m * FD);
        const f32x4* pn = (const f32x4*)(xf + (size_t)n * FD);
        double a0 = 0.0, a1 = 0.0;
        #pragma unroll 4
        for (int k4 = 0; k4 < FD/4; k4 += 2) {
            f32x4 u0 = pm[k4],   vv0 = pn[k4];
            f32x4 u1 = pm[k4+1], vv1 = pn[k4+1];
            a0 = fma((double)u0[0], (double)vv0[0], a0);
            a0 = fma((double)u0[1], (double)vv0[1], a0);
            a0 = fma((double)u0[2], (double)vv0[2], a0);
            a0 = fma((double)u0[3], (double)vv0[3], a0);
            a1 = fma((double)u1[0], (double)vv1[0], a1);
            a1 = fma((double)u1[1], (double)vv1[1], a1);
            a1 = fma((double)u1[2], (double)vv1[2], a1);
            a1 = fma((double)u1[3], (double)vv1[3], a1);
        }
        fval[r*9 + sl] = (a0 + a1) / (nb[m] * nb[n]);
    }
    __syncthreads();

    // ---- exact top-2 (skip diag by index) + publish + own-row writes ----
    if (tid < 64) {
        int m = row0 + tid;
        double bv1 = -1e300, bv2 = -1e300; int bi1 = -1, bi2 = -1;
        #pragma unroll
        for (int cc = 0; cc < 8; ++cc) {
            double v = fval[tid*9 + cc];
            int    n = fidx[tid*9 + cc];
            if (n == m) continue;           // drop self-similarity (diag)
            if (bi1 < 0 || v > bv1 || (v == bv1 && n < bi1)) {
                bv2 = bv1; bi2 = bi1; bv1 = v; bi1 = n;
            } else if (bi2 < 0 || v > bv2 || (v == bv2 && n < bi2)) {
                bv2 = v; bi2 = n;
            }
        }
        // reference top_k competes against the zeroed diagonal (value 0):
        // val1 always scatters; val2 only if it beats the diagonal zero.
        int  i2w = (bv2 > 0.0) ? bi2 : -1;
        int2   si = make_int2(bi1, i2w);
        float2 sv = make_float2((float)(0.5 * bv1), (float)(0.5 * bv2));
        tops_i[(size_t)b * Mdim + m] = si;
        tops_v[(size_t)b * Mdim + m] = sv;
        size_t obase = (size_t)b * Mdim * Mdim + (size_t)m * Mdim;
        out[obase + si.x] = sv.x;           // zeros of this row already written in-loop
        if (si.y >= 0) out[obase + si.y] = sv.y;
    }
}

// ---------- Kernel 3: transpose contributions (unique-writer, non-atomic) ----------
__global__ void transpose_kernel(const int2* __restrict__ tops_i,
                                 const float2* __restrict__ tops_v,
                                 float* out) {
    int id = blockIdx.x * 256 + threadIdx.x;   // 0 .. B*M-1
    int b = id >> 11, m = id & (Mdim - 1);
    int2 si = tops_i[id]; float2 sv = tops_v[id];
    float* ob = out + (size_t)b * Mdim * Mdim;
    float* p1 = ob + (size_t)si.x * Mdim + m;  // column m: only row m writes here
    *p1 += sv.x;
    if (si.y >= 0) {
        float* p2 = ob + (size_t)si.y * Mdim + m;
        *p2 += sv.y;
    }
}

extern "C" void kernel_launch(void* const* d_in, const int* in_sizes, int n_in,
                              void* d_out, int out_size, void* d_ws, size_t ws_size,
                              hipStream_t stream) {
    const float* x = (const float*)d_in[0];
    float* out = (float*)d_out;
    int Bn = in_sizes[0] / (Mdim * FD);   // 16

    char* ws = (char*)d_ws;
    double*         nrm_d  = (double*)ws;                               // 256 KB
    unsigned short* xnb    = (unsigned short*)(ws + 262144);            // 8 MB
    int2*           tops_i = (int2*)(ws + 262144 + 8388608);            // 256 KB
    float2*         tops_v = (float2*)(ws + 262144 + 8388608 + 262144); // 256 KB

    prep_kernel<<<Bn * Mdim / 4, 256, 0, stream>>>(x, nrm_d, xnb);
    topk_kernel<<<Bn * 32, 256, 0, stream>>>(x, xnb, nrm_d, out, tops_i, tops_v);
    transpose_kernel<<<Bn * Mdim / 256, 256, 0, stream>>>(tops_i, tops_v, out);
}

// Round 5
// 329.043 us; speedup vs baseline: 1.3314x; 1.1112x over previous
//
#include <hip/hip_runtime.h>
#include <hip/hip_bf16.h>
#include <math.h>

#define Mdim 2048
#define FD   128

// LDS map (bytes)
#define OFF_FVAL 32768      // double[64][9] = 4608
#define OFF_FIDX 37376      // int[64][9]    = 2304
#define SMEM_SZ  39680      // <= 40960 -> 4 blocks/CU

typedef __attribute__((ext_vector_type(8))) short short8;
typedef __attribute__((ext_vector_type(4))) float f32x4;

// ---------- pack float -> monotone u32 key | 11-bit col index ----------
__device__ __forceinline__ unsigned pkey(float v, int n) {
    unsigned u = __float_as_uint(v);
    unsigned mk = u ^ ((unsigned)((int)u >> 31) | 0x80000000u);
    return (mk & 0xFFFFF800u) | (unsigned)n;
}

// branchless sorted-desc top-3 insert on packed keys
__device__ __forceinline__ void ins3p(unsigned k, unsigned t[3]) {
    bool g2 = k > t[2], g1 = k > t[1], g0 = k > t[0];
    t[2] = g1 ? t[1] : (g2 ? k : t[2]);
    t[1] = g0 ? t[0] : (g1 ? k : t[1]);
    t[0] = g0 ? k : t[0];
}

// sorted-desc top-8 insert with early-out (merge phase, packed keys)
__device__ __forceinline__ void ins8p(unsigned k, unsigned bv[8]) {
    if (k <= bv[7]) return;
    #pragma unroll
    for (int s = 0; s < 8; ++s) {
        if (k > bv[s]) { unsigned o = bv[s]; bv[s] = k; k = o; }
    }
}

// ---------- Kernel 1: fp64 norms + normalized bf16 copy, chunk-swizzled ----------
// xnb row r, physical 16B-chunk p holds logical chunk j = p ^ (r & 15).
__global__ void prep_kernel(const float* __restrict__ x,
                            double* __restrict__ nrm_d,
                            unsigned short* __restrict__ xnb) {
    __shared__ unsigned short sb[4][128];
    int w = threadIdx.x >> 6, lane = threadIdx.x & 63;
    int row = blockIdx.x * 4 + w;
    const float* p = x + (size_t)row * FD;
    float v0 = p[lane], v1 = p[lane + 64];
    double d = (double)v0 * (double)v0 + (double)v1 * (double)v1;
    #pragma unroll
    for (int off = 32; off; off >>= 1) d += __shfl_down(d, off);
    d = __shfl(d, 0);
    double nrm = fmax(sqrt(d), 1e-12);
    if (lane == 0) nrm_d[row] = nrm;
    double inv = 1.0 / nrm;
    __hip_bfloat16 ha = __float2bfloat16((float)((double)v0 * inv));
    __hip_bfloat16 hb = __float2bfloat16((float)((double)v1 * inv));
    sb[w][lane]      = *reinterpret_cast<unsigned short*>(&ha);
    sb[w][lane + 64] = *reinterpret_cast<unsigned short*>(&hb);
    __syncthreads();
    if (lane < 16) {
        int j = lane ^ (row & 15);   // logical chunk stored at physical 'lane'
        short8 v = *(const short8*)&sb[w][j * 8];
        *(short8*)(xnb + (size_t)row * FD + lane * 8) = v;
    }
}

// ---------- Kernel 2: MFMA GEMM + packed top-k + fp64 refine + dense write ----------
__launch_bounds__(256, 4)
__global__ void topk_kernel(const float* __restrict__ x,
                            const unsigned short* __restrict__ xnb,
                            const double* __restrict__ nrm_d,
                            float* __restrict__ out,
                            int2* __restrict__ tops_i,
                            float2* __restrict__ tops_v) {
    __shared__ __align__(16) char smem[SMEM_SZ];
    unsigned short* Bld = (unsigned short*)smem;  // [128 cols][128 k], source-swizzled

    int b  = blockIdx.x >> 5;
    int rt = blockIdx.x & 31;
    int row0 = rt * 64;
    const unsigned short* xb = xnb + (size_t)b * Mdim * FD;

    int tid  = threadIdx.x;
    int lane = tid & 63;
    int w    = tid >> 6;
    int wy   = w >> 1, wx = w & 1;     // wave tile: 32 rows x 64 cols
    int c    = lane & 15, q = lane >> 4;

    // A fragments (global chunks swizzled by row)
    short8 afr[2][4];
    #pragma unroll
    for (int rs = 0; rs < 2; ++rs)
        #pragma unroll
        for (int s = 0; s < 4; ++s) {
            int row = row0 + wy*32 + rs*16 + c;
            int p = ((s << 2) + q) ^ (row & 15);
            afr[rs][s] = *(const short8*)(xb + (size_t)row * FD + p * 8);
        }

    // per-lane packed top-3 per owned row (8 rows/lane)
    unsigned tvp[8][3];
    #pragma unroll
    for (int i = 0; i < 8; ++i) { tvp[i][0] = 0; tvp[i][1] = 0; tvp[i][2] = 0; }

    float* zbase = out + (size_t)b * Mdim * Mdim
                 + (size_t)(row0 + (tid >> 5)) * Mdim + (tid & 31) * 4;

    #pragma unroll 1
    for (int ch = 0; ch < Mdim / 128; ++ch) {
        int col0 = ch * 128;
        __syncthreads();
        {   // DMA stage: wave w covers cols [w*32, w*32+32), 8 issues of 1KB
            #pragma unroll
            for (int i = 0; i < 8; ++i) {
                const void* gp = xb + (size_t)(col0 + w*32 + i*4 + (lane >> 4)) * FD
                               + (lane & 15) * 8;
                void* lp = smem + ((w*32 + i*4) * 128) * sizeof(unsigned short);
                __builtin_amdgcn_global_load_lds(
                    (const __attribute__((address_space(1))) unsigned*)gp,
                    (__attribute__((address_space(3))) unsigned*)lp, 16, 0, 0);
            }
        }
        __syncthreads();

        // zero-write this chunk's output slice (overlaps MFMA latency)
        {
            float4 z = make_float4(0.f, 0.f, 0.f, 0.f);
            #pragma unroll
            for (int t = 0; t < 8; ++t)
                *(float4*)(zbase + (size_t)t * 8 * Mdim) = z;
            zbase += 128;
        }

        f32x4 acc[2][4];
        #pragma unroll
        for (int rs = 0; rs < 2; ++rs)
            #pragma unroll
            for (int ct = 0; ct < 4; ++ct)
                acc[rs][ct] = (f32x4){0.f, 0.f, 0.f, 0.f};

        #pragma unroll
        for (int s = 0; s < 4; ++s)
            #pragma unroll
            for (int ct = 0; ct < 4; ++ct) {
                int p = ((s << 2) + q) ^ c;   // swizzle key = col & 15 = c
                short8 bfr = *(const short8*)(Bld + (size_t)(wx*64 + ct*16 + c) * 128 + p * 8);
                acc[0][ct] = __builtin_amdgcn_mfma_f32_16x16x32_bf16(afr[0][s], bfr, acc[0][ct], 0, 0, 0);
                acc[1][ct] = __builtin_amdgcn_mfma_f32_16x16x32_bf16(afr[1][s], bfr, acc[1][ct], 0, 0, 0);
            }

        // scan on packed keys (diag included; dropped at final select)
        int nbase = col0 + wx*64 + c;
        #pragma unroll
        for (int rs = 0; rs < 2; ++rs)
            #pragma unroll
            for (int i = 0; i < 4; ++i) {
                int rr = rs*4 + i;
                unsigned k0 = pkey(acc[rs][0][i], nbase);
                unsigned k1 = pkey(acc[rs][1][i], nbase + 16);
                unsigned k2 = pkey(acc[rs][2][i], nbase + 32);
                unsigned k3 = pkey(acc[rs][3][i], nbase + 48);
                unsigned mx = max(max(k0, k1), max(k2, k3));
                if (mx > tvp[rr][2]) {
                    ins3p(k0, tvp[rr]);
                    ins3p(k1, tvp[rr]);
                    ins3p(k2, tvp[rr]);
                    ins3p(k3, tvp[rr]);
                }
            }
    }

    // ---- merge: per-lane top-3 -> per-row pool of 96 packed keys ----
    __syncthreads();
    unsigned* mpool = (unsigned*)smem;      // [64][97], reuses Bld
    {
        int slot = wx*16 + c;
        #pragma unroll
        for (int rs = 0; rs < 2; ++rs)
            #pragma unroll
            for (int i = 0; i < 4; ++i) {
                int rloc = wy*32 + rs*16 + q*4 + i;
                #pragma unroll
                for (int j = 0; j < 3; ++j)
                    mpool[rloc*97 + slot*3 + j] = tvp[rs*4 + i][j];
            }
    }
    __syncthreads();

    double* fval = (double*)(smem + OFF_FVAL);   // [64][9]
    int*    fidx = (int*)(smem + OFF_FIDX);      // [64][9]
    if (tid < 64) {
        unsigned bv[8];
        #pragma unroll
        for (int s = 0; s < 8; ++s) bv[s] = 0;
        for (int s2 = 0; s2 < 96; ++s2)
            ins8p(mpool[tid*97 + s2], bv);
        #pragma unroll
        for (int s = 0; s < 8; ++s) fidx[tid*9 + s] = (int)(bv[s] & 2047u);
    }
    __syncthreads();

    // ---- fp64 refinement: 512 candidates, 2 per thread (raw fp32 x) ----
    const float*  xf = x + (size_t)b * Mdim * FD;
    const double* nb = nrm_d + (size_t)b * Mdim;
    #pragma unroll
    for (int it = 0; it < 2; ++it) {
        int id = tid + it * 256;
        int r = id >> 3, sl = id & 7;
        int n = fidx[r*9 + sl];
        int m = row0 + r;
        const f32x4* pm = (const f32x4*)(xf + (size_t)m * FD);
        const f32x4* pn = (const f32x4*)(xf + (size_t)n * FD);
        double a0 = 0.0, a1 = 0.0;
        #pragma unroll 4
        for (int k4 = 0; k4 < FD/4; k4 += 2) {
            f32x4 u0 = pm[k4],   vv0 = pn[k4];
            f32x4 u1 = pm[k4+1], vv1 = pn[k4+1];
            a0 = fma((double)u0[0], (double)vv0[0], a0);
            a0 = fma((double)u0[1], (double)vv0[1], a0);
            a0 = fma((double)u0[2], (double)vv0[2], a0);
            a0 = fma((double)u0[3], (double)vv0[3], a0);
            a1 = fma((double)u1[0], (double)vv1[0], a1);
            a1 = fma((double)u1[1], (double)vv1[1], a1);
            a1 = fma((double)u1[2], (double)vv1[2], a1);
            a1 = fma((double)u1[3], (double)vv1[3], a1);
        }
        fval[r*9 + sl] = (a0 + a1) / (nb[m] * nb[n]);
    }
    __syncthreads();

    // ---- exact top-2 (skip diag by index) + publish + own-row point writes ----
    if (tid < 64) {
        int m = row0 + tid;
        double bv1 = -1e300, bv2 = -1e300; int bi1 = -1, bi2 = -1;
        #pragma unroll
        for (int cc = 0; cc < 8; ++cc) {
            double v = fval[tid*9 + cc];
            int    n = fidx[tid*9 + cc];
            if (n == m) continue;
            if (bi1 < 0 || v > bv1 || (v == bv1 && n < bi1)) {
                bv2 = bv1; bi2 = bi1; bv1 = v; bi1 = n;
            } else if (bi2 < 0 || v > bv2 || (v == bv2 && n < bi2)) {
                bv2 = v; bi2 = n;
            }
        }
        // reference top_k competes against the zeroed diagonal (value 0):
        // val1 always scatters; val2 only if it beats the diagonal zero.
        int  i2w = (bv2 > 0.0) ? bi2 : -1;
        int2   si = make_int2(bi1, i2w);
        float2 sv = make_float2((float)(0.5 * bv1), (float)(0.5 * bv2));
        tops_i[(size_t)b * Mdim + m] = si;
        tops_v[(size_t)b * Mdim + m] = sv;
        size_t obase = (size_t)b * Mdim * Mdim + (size_t)m * Mdim;
        out[obase + si.x] = sv.x;
        if (si.y >= 0) out[obase + si.y] = sv.y;
    }
}

// ---------- Kernel 3: transpose contributions (unique-writer, non-atomic) ----------
__global__ void transpose_kernel(const int2* __restrict__ tops_i,
                                 const float2* __restrict__ tops_v,
                                 float* out) {
    int id = blockIdx.x * 256 + threadIdx.x;
    int b = id >> 11, m = id & (Mdim - 1);
    int2 si = tops_i[id]; float2 sv = tops_v[id];
    float* ob = out + (size_t)b * Mdim * Mdim;
    float* p1 = ob + (size_t)si.x * Mdim + m;
    *p1 += sv.x;
    if (si.y >= 0) {
        float* p2 = ob + (size_t)si.y * Mdim + m;
        *p2 += sv.y;
    }
}

extern "C" void kernel_launch(void* const* d_in, const int* in_sizes, int n_in,
                              void* d_out, int out_size, void* d_ws, size_t ws_size,
                              hipStream_t stream) {
    const float* x = (const float*)d_in[0];
    float* out = (float*)d_out;
    int Bn = in_sizes[0] / (Mdim * FD);   // 16

    char* ws = (char*)d_ws;
    double*         nrm_d  = (double*)ws;
    unsigned short* xnb    = (unsigned short*)(ws + 262144);
    int2*           tops_i = (int2*)(ws + 262144 + 8388608);
    float2*         tops_v = (float2*)(ws + 262144 + 8388608 + 262144);

    prep_kernel<<<Bn * Mdim / 4, 256, 0, stream>>>(x, nrm_d, xnb);
    topk_kernel<<<Bn * 32, 256, 0, stream>>>(x, xnb, nrm_d, out, tops_i, tops_v);
    transpose_kernel<<<Bn * Mdim / 256, 256, 0, stream>>>(tops_i, tops_v, out);
}